// Round 1
// baseline (1919.689 us; speedup 1.0000x reference)
//
#include <hip/hip_runtime.h>

// Problem: B=2, S=2048, D=1024, H=16, DK=64.
// Outputs: out [B,S,D] (4194304 f32) then attn [B,H,S,S] (134217728 f32).
// Round 0: correct fp32 baseline, 5 kernels. No MFMA yet (no fp32 MFMA on CDNA4).

#define Bsz 2
#define Ssz 2048
#define Dsz 1024
#define Hsz 16
#define DKsz 64
#define Msz (Bsz * Ssz)  // 4096

// ---------------------------------------------------------------------------
// Tiled fp32 GEMM building block: BM=BN=64, BK=16, 256 threads, 4x4/thread.
// A [M,K] row-major, W [N,K] row-major, C = A * W^T.
// ---------------------------------------------------------------------------

// Kernel 1: QKV projection.  z selects (X, W, O).  Output written in
// split-heads layout O[((b*H+h)*S + s)*DK + dk] with h = n>>6, dk = n&63.
__global__ __launch_bounds__(256) void qkv_proj_k(
    const float* __restrict__ Xq, const float* __restrict__ Xk,
    const float* __restrict__ Xv, const float* __restrict__ Wq,
    const float* __restrict__ Wk, const float* __restrict__ Wv,
    float* __restrict__ Qo, float* __restrict__ Ko, float* __restrict__ Vo) {
  const float* A;
  const float* W;
  float* O;
  const int z = blockIdx.z;
  if (z == 0) { A = Xq; W = Wq; O = Qo; }
  else if (z == 1) { A = Xk; W = Wk; O = Ko; }
  else { A = Xv; W = Wv; O = Vo; }

  __shared__ float As[16][65];  // [k][m], +1 pad
  __shared__ float Ws[16][65];  // [k][n], +1 pad
  const int t = threadIdx.x;
  const int tx = t & 15, ty = t >> 4;
  const int m0 = blockIdx.y * 64;
  const int n0 = blockIdx.x * 64;

  float acc[4][4] = {};
  for (int k0 = 0; k0 < Dsz; k0 += 16) {
#pragma unroll
    for (int i = 0; i < 4; i++) {
      const int idx = t + i * 256;
      const int r = idx >> 4, c = idx & 15;
      As[c][r] = A[(size_t)(m0 + r) * Dsz + k0 + c];
      Ws[c][r] = W[(size_t)(n0 + r) * Dsz + k0 + c];
    }
    __syncthreads();
#pragma unroll
    for (int kk = 0; kk < 16; kk++) {
      float a[4], b[4];
#pragma unroll
      for (int i = 0; i < 4; i++) a[i] = As[kk][ty * 4 + i];
#pragma unroll
      for (int j = 0; j < 4; j++) b[j] = Ws[kk][tx * 4 + j];
#pragma unroll
      for (int i = 0; i < 4; i++)
#pragma unroll
        for (int j = 0; j < 4; j++) acc[i][j] += a[i] * b[j];
    }
    __syncthreads();
  }
  // epilogue: n-tile of 64 == one head (h = blockIdx.x); rows all in one b.
  const int h = blockIdx.x;
  const int b = m0 >> 11;
  const int s_base = (m0 & 2047) + ty * 4;
#pragma unroll
  for (int i = 0; i < 4; i++) {
    const int s = s_base + i;
    float* dst = O + ((size_t)((b * Hsz + h) * Ssz + s)) * DKsz + tx * 4;
#pragma unroll
    for (int j = 0; j < 4; j++) dst[j] = acc[i][j];
  }
}

// Kernel 2: raw scaled scores -> attn region.  Per (b,h): [S,S] = Q [S,DK] * K^T.
__global__ __launch_bounds__(256) void scores_k(
    const float* __restrict__ Q, const float* __restrict__ K,
    float* __restrict__ attn) {
  const int z = blockIdx.z;  // bh in [0,32)
  const float* Qb = Q + (size_t)z * Ssz * DKsz;
  const float* Kb = K + (size_t)z * Ssz * DKsz;
  float* Ab = attn + (size_t)z * Ssz * Ssz;

  __shared__ float Qs[16][65];
  __shared__ float Ks[16][65];
  const int t = threadIdx.x;
  const int tx = t & 15, ty = t >> 4;
  const int m0 = blockIdx.y * 64;
  const int n0 = blockIdx.x * 64;

  float acc[4][4] = {};
  for (int k0 = 0; k0 < DKsz; k0 += 16) {
#pragma unroll
    for (int i = 0; i < 4; i++) {
      const int idx = t + i * 256;
      const int r = idx >> 4, c = idx & 15;
      Qs[c][r] = Qb[(size_t)(m0 + r) * DKsz + k0 + c];
      Ks[c][r] = Kb[(size_t)(n0 + r) * DKsz + k0 + c];
    }
    __syncthreads();
#pragma unroll
    for (int kk = 0; kk < 16; kk++) {
      float a[4], b[4];
#pragma unroll
      for (int i = 0; i < 4; i++) a[i] = Qs[kk][ty * 4 + i];
#pragma unroll
      for (int j = 0; j < 4; j++) b[j] = Ks[kk][tx * 4 + j];
#pragma unroll
      for (int i = 0; i < 4; i++)
#pragma unroll
        for (int j = 0; j < 4; j++) acc[i][j] += a[i] * b[j];
    }
    __syncthreads();
  }
#pragma unroll
  for (int i = 0; i < 4; i++) {
    float* dst = Ab + (size_t)(m0 + ty * 4 + i) * Ssz + n0 + tx * 4;
#pragma unroll
    for (int j = 0; j < 4; j++) dst[j] = acc[i][j] * 0.125f;  // 1/sqrt(64)
  }
}

// Kernel 3: row-wise softmax in place over attn (rows of 2048).
__global__ __launch_bounds__(256) void softmax_k(float* __restrict__ attn) {
  float* p = attn + (size_t)blockIdx.x * Ssz;
  const int t = threadIdx.x;
  float4 v0 = ((const float4*)p)[t];
  float4 v1 = ((const float4*)p)[t + 256];

  float mx = fmaxf(fmaxf(fmaxf(v0.x, v0.y), fmaxf(v0.z, v0.w)),
                   fmaxf(fmaxf(v1.x, v1.y), fmaxf(v1.z, v1.w)));
  __shared__ float red[256];
  red[t] = mx;
  __syncthreads();
  for (int o = 128; o > 0; o >>= 1) {
    if (t < o) red[t] = fmaxf(red[t], red[t + o]);
    __syncthreads();
  }
  const float rmax = red[0];
  __syncthreads();

  v0.x = __expf(v0.x - rmax); v0.y = __expf(v0.y - rmax);
  v0.z = __expf(v0.z - rmax); v0.w = __expf(v0.w - rmax);
  v1.x = __expf(v1.x - rmax); v1.y = __expf(v1.y - rmax);
  v1.z = __expf(v1.z - rmax); v1.w = __expf(v1.w - rmax);
  float sm = (v0.x + v0.y + v0.z + v0.w) + (v1.x + v1.y + v1.z + v1.w);
  red[t] = sm;
  __syncthreads();
  for (int o = 128; o > 0; o >>= 1) {
    if (t < o) red[t] += red[t + o];
    __syncthreads();
  }
  const float inv = 1.0f / red[0];

  v0.x *= inv; v0.y *= inv; v0.z *= inv; v0.w *= inv;
  v1.x *= inv; v1.y *= inv; v1.z *= inv; v1.w *= inv;
  ((float4*)p)[t] = v0;
  ((float4*)p)[t + 256] = v1;
}

// Kernel 4: ctx = attn * V per (b,h).  [S,DK] = [S,S] * [S,DK].
// Output in merged layout ctx[(b*S+s)*D + h*DK + dk].
__global__ __launch_bounds__(256) void ctx_k(
    const float* __restrict__ attn, const float* __restrict__ V,
    float* __restrict__ ctx) {
  const int z = blockIdx.z;  // bh
  const float* Ab = attn + (size_t)z * Ssz * Ssz;
  const float* Vb = V + (size_t)z * Ssz * DKsz;

  __shared__ float As[16][65];  // [k][m]
  __shared__ float Vs[16][64];  // [k][n]
  const int t = threadIdx.x;
  const int tx = t & 15, ty = t >> 4;
  const int m0 = blockIdx.y * 64;

  float acc[4][4] = {};
  for (int k0 = 0; k0 < Ssz; k0 += 16) {
#pragma unroll
    for (int i = 0; i < 4; i++) {
      const int idx = t + i * 256;
      const int r = idx >> 4, c = idx & 15;
      As[c][r] = Ab[(size_t)(m0 + r) * Ssz + k0 + c];
    }
#pragma unroll
    for (int i = 0; i < 4; i++) {
      const int idx = t + i * 256;
      const int r = idx >> 6, c = idx & 63;
      Vs[r][c] = Vb[(size_t)(k0 + r) * DKsz + c];
    }
    __syncthreads();
#pragma unroll
    for (int kk = 0; kk < 16; kk++) {
      float a[4], b[4];
#pragma unroll
      for (int i = 0; i < 4; i++) a[i] = As[kk][ty * 4 + i];
#pragma unroll
      for (int j = 0; j < 4; j++) b[j] = Vs[kk][tx * 4 + j];
#pragma unroll
      for (int i = 0; i < 4; i++)
#pragma unroll
        for (int j = 0; j < 4; j++) acc[i][j] += a[i] * b[j];
    }
    __syncthreads();
  }
  const int b = z >> 4, h = z & 15;
#pragma unroll
  for (int i = 0; i < 4; i++) {
    const int s = m0 + ty * 4 + i;
    float* dst = ctx + (size_t)(b * Ssz + s) * Dsz + h * DKsz + tx * 4;
#pragma unroll
    for (int j = 0; j < 4; j++) dst[j] = acc[i][j];
  }
}

// Kernel 5: out = ctx * Wo^T, plain [M,N] row-major output.
__global__ __launch_bounds__(256) void out_proj_k(
    const float* __restrict__ A, const float* __restrict__ W,
    float* __restrict__ C) {
  __shared__ float As[16][65];
  __shared__ float Ws[16][65];
  const int t = threadIdx.x;
  const int tx = t & 15, ty = t >> 4;
  const int m0 = blockIdx.y * 64;
  const int n0 = blockIdx.x * 64;

  float acc[4][4] = {};
  for (int k0 = 0; k0 < Dsz; k0 += 16) {
#pragma unroll
    for (int i = 0; i < 4; i++) {
      const int idx = t + i * 256;
      const int r = idx >> 4, c = idx & 15;
      As[c][r] = A[(size_t)(m0 + r) * Dsz + k0 + c];
      Ws[c][r] = W[(size_t)(n0 + r) * Dsz + k0 + c];
    }
    __syncthreads();
#pragma unroll
    for (int kk = 0; kk < 16; kk++) {
      float a[4], b[4];
#pragma unroll
      for (int i = 0; i < 4; i++) a[i] = As[kk][ty * 4 + i];
#pragma unroll
      for (int j = 0; j < 4; j++) b[j] = Ws[kk][tx * 4 + j];
#pragma unroll
      for (int i = 0; i < 4; i++)
#pragma unroll
        for (int j = 0; j < 4; j++) acc[i][j] += a[i] * b[j];
    }
    __syncthreads();
  }
#pragma unroll
  for (int i = 0; i < 4; i++) {
    float* dst = C + (size_t)(m0 + ty * 4 + i) * Dsz + n0 + tx * 4;
#pragma unroll
    for (int j = 0; j < 4; j++) dst[j] = acc[i][j];
  }
}

extern "C" void kernel_launch(void* const* d_in, const int* in_sizes, int n_in,
                              void* d_out, int out_size, void* d_ws,
                              size_t ws_size, hipStream_t stream) {
  const float* Xq = (const float*)d_in[0];
  const float* Xk = (const float*)d_in[1];
  const float* Xv = (const float*)d_in[2];
  const float* Wq = (const float*)d_in[3];
  const float* Wk = (const float*)d_in[4];
  const float* Wv = (const float*)d_in[5];
  const float* Wo = (const float*)d_in[6];

  float* out = (float*)d_out;                       // [B,S,D]
  float* attn = out + (size_t)Msz * Dsz;            // [B,H,S,S]

  // Workspace: Q,K,V in [B,H,S,DK] + ctx in [B,S,D]  (64 MB fp32 total)
  float* Q = (float*)d_ws;
  float* K = Q + (size_t)Msz * Dsz;
  float* V = K + (size_t)Msz * Dsz;
  float* ctx = V + (size_t)Msz * Dsz;

  qkv_proj_k<<<dim3(16, 64, 3), 256, 0, stream>>>(Xq, Xk, Xv, Wq, Wk, Wv, Q, K, V);
  scores_k<<<dim3(32, 32, 32), 256, 0, stream>>>(Q, K, attn);
  softmax_k<<<dim3(65536, 1, 1), 256, 0, stream>>>(attn);
  ctx_k<<<dim3(1, 32, 32), 256, 0, stream>>>(attn, V, ctx);
  out_proj_k<<<dim3(16, 64, 1), 256, 0, stream>>>(ctx, Wo, out);
}